// Round 9
// baseline (239.874 us; speedup 1.0000x reference)
//
#include <hip/hip_runtime.h>

// Feature dims fixed by the problem
constexpr int FIN = 64;   // input features
constexpr int FH  = 64;   // hidden
constexpr int FO  = 16;   // output

// edge_index arrives as int32 (harness integer convention), flat [2][E]:
// src = ei[e], dst = ei[e + E].

// Bucket sort parameters: bucket = dst >> 7 (128 nodes per bucket).
constexpr int BSH      = 7;
constexpr int BW       = 1 << BSH;  // 128 nodes / bucket
constexpr int NBUCK    = 1024;      // covers N up to 131072
constexpr int EPB_HIST = 16384;     // edges per hist block
constexpr int EPB_BIN  = 4096;      // edges per binning block

// bf16 helpers (manual RNE; exact expand)
__device__ inline unsigned short f2bf(float f) {
    unsigned u = __float_as_uint(f);
    return (unsigned short)((u + 0x7FFFu + ((u >> 16) & 1u)) >> 16);
}
__device__ inline float bf2f(unsigned short h) {
    return __uint_as_float((unsigned)h << 16);
}
__device__ inline float4 bf4_to_f4(ushort4 u) {
    float4 f;
    f.x = bf2f(u.x); f.y = bf2f(u.y); f.z = bf2f(u.z); f.w = bf2f(u.w);
    return f;
}

// ---------------------------------------------------------------------------
// Kernel: dst-bucket histogram (standalone; 98 blocks, cheap).
// ---------------------------------------------------------------------------
__launch_bounds__(256)
__global__ void hist_kernel(const int* __restrict__ ei, int E, int* __restrict__ bcnt) {
    __shared__ int lh[NBUCK];
    int t = threadIdx.x;
    for (int i = t; i < NBUCK; i += 256) lh[i] = 0;
    __syncthreads();
    int base = blockIdx.x * EPB_HIST;
    int lim  = min(E, base + EPB_HIST);
    for (int e = base + t; e < lim; e += 256)
        atomicAdd(&lh[ei[E + e] >> BSH], 1);
    __syncthreads();
    for (int b = t; b < NBUCK; b += 256) {
        int c = lh[b];
        if (c > 0) atomicAdd(&bcnt[b], c);
    }
}

// ---------------------------------------------------------------------------
// Kernel: exclusive scan of bucket counts -> bbase[NBUCK+1], init gcur.
// Single block of 1024 threads. Also writes offs[N] = E.
// ---------------------------------------------------------------------------
__launch_bounds__(1024)
__global__ void bucket_scan_kernel(const int* __restrict__ bcnt, int* __restrict__ bbase,
                                   int* __restrict__ gcur, int* __restrict__ offs,
                                   int N, int E) {
    __shared__ int s[NBUCK];
    int t = threadIdx.x;
    int v = bcnt[t];
    s[t] = v;
    __syncthreads();
    for (int d = 1; d < NBUCK; d <<= 1) {
        int u = (t >= d) ? s[t - d] : 0;
        __syncthreads();
        s[t] += u;
        __syncthreads();
    }
    int ex = s[t] - v;
    bbase[t] = ex;
    gcur[t]  = ex;
    if (t == NBUCK - 1) {
        bbase[NBUCK] = s[t];   // == E
        offs[N] = E;
    }
}

// ---------------------------------------------------------------------------
// Binning device body: reserve contiguous per-bucket runs, write each edge
// once as packed word src | (dst & 127) << 17 (N < 2^17).
// ---------------------------------------------------------------------------
__device__ inline void binning_body(const int* __restrict__ ei, int E, int chunk,
                                    int* __restrict__ gcur, unsigned* __restrict__ ebuf,
                                    int* lh) {
    int t = threadIdx.x;
    for (int i = t; i < NBUCK; i += 256) lh[i] = 0;
    __syncthreads();
    int base = chunk * EPB_BIN;
    int lim  = min(E, base + EPB_BIN);
    for (int e = base + t; e < lim; e += 256)
        atomicAdd(&lh[ei[E + e] >> BSH], 1);
    __syncthreads();
    for (int b = t; b < NBUCK; b += 256) {
        int c = lh[b];
        lh[b] = (c > 0) ? atomicAdd(&gcur[b], c) : 0;   // run base -> running cursor
    }
    __syncthreads();
    for (int e = base + t; e < lim; e += 256) {
        int d = ei[E + e];
        int srcv = ei[e];
        int pos = atomicAdd(&lh[d >> BSH], 1);
        ebuf[pos] = (unsigned)srcv | ((unsigned)(d & (BW - 1)) << 17);
    }
}

__launch_bounds__(256)
__global__ void binning_kernel(const int* __restrict__ ei, int E,
                               int* __restrict__ gcur, unsigned* __restrict__ ebuf) {
    __shared__ int lh[NBUCK];
    binning_body(ei, E, blockIdx.x, gcur, ebuf, lh);
}

// ---------------------------------------------------------------------------
// Fused kernel: blocks [0, NBIN) do binning (latency-bound, start first);
// blocks [NBIN, NBIN+G1T) do hs_bf16 = bf16(x @ W1): 64-row tile, x kept in
// REGISTERS (double-buffered k-chunks, 16-lane broadcast loads), only W1 in
// LDS (16 KB, conflict-free reads) -> high occupancy, zero transpose staging.
// ---------------------------------------------------------------------------
__launch_bounds__(256)
__global__ void gemm1_binning_kernel(const float* __restrict__ x, const float* __restrict__ W1,
                                     unsigned short* __restrict__ hsb,
                                     const int* __restrict__ ei, int E,
                                     int* __restrict__ gcur, unsigned* __restrict__ ebuf,
                                     int N, int NBIN) {
    __shared__ float smem[FIN * FH];    // 16 KB: Ws for gemm, lh (4 KB) for binning
    int tid = threadIdx.x;
    if ((int)blockIdx.x < NBIN) {
        binning_body(ei, E, (int)blockIdx.x, gcur, ebuf, (int*)smem);
        return;
    }
    // ---- GEMM phase ----
    float* Ws = smem;                  // [64][64] row-major (k, col)
    {
        const float4* W14 = (const float4*)W1;
        float4* Ws4 = (float4*)smem;
        for (int i = tid; i < 1024; i += 256) Ws4[i] = W14[i];
    }
    __syncthreads();
    int cg = tid & 15;                 // col group: cols cg*4..+3
    int rg = tid >> 4;                 // row group: rows rg*4..+3
    int rowBase = ((int)blockIdx.x - NBIN) * 64;
    int r0 = rowBase + rg * 4;
    const float4* x4 = (const float4*)x;
    // clamped row indices (loads never fault; OOB rows' stores are predicated)
    size_t ra = (size_t)min(r0 + 0, N - 1) * 16;
    size_t rb = (size_t)min(r0 + 1, N - 1) * 16;
    size_t rc = (size_t)min(r0 + 2, N - 1) * 16;
    size_t rd = (size_t)min(r0 + 3, N - 1) * 16;
    float4 acc0 = {0,0,0,0}, acc1 = {0,0,0,0}, acc2 = {0,0,0,0}, acc3 = {0,0,0,0};
    float4 xa0 = x4[ra], xa1 = x4[rb], xa2 = x4[rc], xa3 = x4[rd];
    #pragma unroll
    for (int kc = 0; kc < 16; ++kc) {
        float4 xb0, xb1, xb2, xb3;
        if (kc < 15) {                 // prefetch next k-chunk
            xb0 = x4[ra + kc + 1]; xb1 = x4[rb + kc + 1];
            xb2 = x4[rc + kc + 1]; xb3 = x4[rd + kc + 1];
        }
        const float* xa0f = (const float*)&xa0;
        const float* xa1f = (const float*)&xa1;
        const float* xa2f = (const float*)&xa2;
        const float* xa3f = (const float*)&xa3;
        #pragma unroll
        for (int j = 0; j < 4; ++j) {
            float4 wv = *(const float4*)&Ws[(kc * 4 + j) * FH + cg * 4];
            float v0 = xa0f[j], v1 = xa1f[j], v2 = xa2f[j], v3 = xa3f[j];
            acc0.x = fmaf(v0, wv.x, acc0.x); acc0.y = fmaf(v0, wv.y, acc0.y);
            acc0.z = fmaf(v0, wv.z, acc0.z); acc0.w = fmaf(v0, wv.w, acc0.w);
            acc1.x = fmaf(v1, wv.x, acc1.x); acc1.y = fmaf(v1, wv.y, acc1.y);
            acc1.z = fmaf(v1, wv.z, acc1.z); acc1.w = fmaf(v1, wv.w, acc1.w);
            acc2.x = fmaf(v2, wv.x, acc2.x); acc2.y = fmaf(v2, wv.y, acc2.y);
            acc2.z = fmaf(v2, wv.z, acc2.z); acc2.w = fmaf(v2, wv.w, acc2.w);
            acc3.x = fmaf(v3, wv.x, acc3.x); acc3.y = fmaf(v3, wv.y, acc3.y);
            acc3.z = fmaf(v3, wv.z, acc3.z); acc3.w = fmaf(v3, wv.w, acc3.w);
        }
        xa0 = xb0; xa1 = xb1; xa2 = xb2; xa3 = xb3;
    }
    ushort4* hsb4 = (ushort4*)hsb;
    if (r0 + 0 < N) hsb4[(size_t)(r0 + 0) * 16 + cg] =
        make_ushort4(f2bf(acc0.x), f2bf(acc0.y), f2bf(acc0.z), f2bf(acc0.w));
    if (r0 + 1 < N) hsb4[(size_t)(r0 + 1) * 16 + cg] =
        make_ushort4(f2bf(acc1.x), f2bf(acc1.y), f2bf(acc1.z), f2bf(acc1.w));
    if (r0 + 2 < N) hsb4[(size_t)(r0 + 2) * 16 + cg] =
        make_ushort4(f2bf(acc2.x), f2bf(acc2.y), f2bf(acc2.z), f2bf(acc2.w));
    if (r0 + 3 < N) hsb4[(size_t)(r0 + 3) * 16 + cg] =
        make_ushort4(f2bf(acc3.x), f2bf(acc3.y), f2bf(acc3.z), f2bf(acc3.w));
}

// ---------------------------------------------------------------------------
// Kernel: per-bucket CSR build + dinv + offs. One block per bucket; all csr
// stores land in the block's own contiguous region (single-owner lines).
// ---------------------------------------------------------------------------
__launch_bounds__(256)
__global__ void bucket_csr_kernel(const unsigned* __restrict__ ebuf,
                                  const int* __restrict__ bbase,
                                  int* __restrict__ csr, int* __restrict__ offs,
                                  float* __restrict__ dinv, int N) {
    __shared__ int cnt[BW], sc[BW], cur[BW];
    int t = threadIdx.x;
    int b = blockIdx.x;
    if (t < BW) cnt[t] = 0;
    __syncthreads();
    int beg = bbase[b], end = bbase[b + 1];
    for (int i = beg + t; i < end; i += 256)
        atomicAdd(&cnt[ebuf[i] >> 17], 1);
    __syncthreads();
    if (t < BW) sc[t] = cnt[t];
    __syncthreads();
    for (int d = 1; d < BW; d <<= 1) {
        int u = (t < BW && t >= d) ? sc[t - d] : 0;
        __syncthreads();
        if (t < BW) sc[t] += u;
        __syncthreads();
    }
    int nodeBase = b << BSH;
    if (t < BW) {
        int node = nodeBase + t;
        int ex = beg + sc[t] - cnt[t];
        cur[t] = ex;
        if (node < N) {
            offs[node] = ex;
            dinv[node] = rsqrtf((float)(cnt[t] + 1));
        }
    }
    __syncthreads();
    for (int i = beg + t; i < end; i += 256) {
        unsigned w = ebuf[i];
        int pos = atomicAdd(&cur[w >> 17], 1);
        csr[pos] = (int)(w & 0x1FFFF);
    }
}

// ---------------------------------------------------------------------------
// Kernel: layer-1 PULL aggregation (bf16 gathers, 8 in flight, per-src dinv
// scale in-reg) fused with finalize1 + GEMM2; writes hs2 pre-scaled as bf16.
// 16 nodes/block; 16 lanes per node, lane owns one ushort4 chunk (4 feats).
// ---------------------------------------------------------------------------
__launch_bounds__(256)
__global__ void agg1_gemm2_kernel(const unsigned short* __restrict__ hsb,
                                  const int* __restrict__ csr,
                                  const int* __restrict__ offs, const float* __restrict__ dinv,
                                  const float* __restrict__ b1, const float* __restrict__ W2,
                                  unsigned short* __restrict__ hs2b, int N) {
    __shared__ float W2s[FH * FO];       // 4 KB
    __shared__ float h1s[16][68];        // 68-float row stride (16B-aligned, non-pow2)
    const ushort4* hs4 = (const ushort4*)hsb;   // 16 ushort4 per row
    int tid = threadIdx.x;
    for (int i = tid; i < FH * FO; i += 256) W2s[i] = W2[i];
    int g = tid >> 4, l = tid & 15;
    int n = blockIdx.x * 16 + g;
    if (n < N) {
        float di_n = dinv[n];
        float4 self = bf4_to_f4(hs4[(size_t)n * 16 + l]);
        float4 acc;
        acc.x = self.x * di_n; acc.y = self.y * di_n;
        acc.z = self.z * di_n; acc.w = self.w * di_n;
        int j = offs[n], end = offs[n + 1];
        for (; j + 7 < end; j += 8) {              // 8 gathers in flight
            int s0 = csr[j],     s1 = csr[j + 1], s2 = csr[j + 2], s3 = csr[j + 3];
            int s4 = csr[j + 4], s5 = csr[j + 5], s6 = csr[j + 6], s7 = csr[j + 7];
            float d0 = dinv[s0], d1 = dinv[s1], d2 = dinv[s2], d3 = dinv[s3];
            float d4 = dinv[s4], d5 = dinv[s5], d6 = dinv[s6], d7 = dinv[s7];
            float4 a0 = bf4_to_f4(hs4[(size_t)s0 * 16 + l]);
            float4 a1 = bf4_to_f4(hs4[(size_t)s1 * 16 + l]);
            float4 a2 = bf4_to_f4(hs4[(size_t)s2 * 16 + l]);
            float4 a3 = bf4_to_f4(hs4[(size_t)s3 * 16 + l]);
            float4 a4 = bf4_to_f4(hs4[(size_t)s4 * 16 + l]);
            float4 a5 = bf4_to_f4(hs4[(size_t)s5 * 16 + l]);
            float4 a6 = bf4_to_f4(hs4[(size_t)s6 * 16 + l]);
            float4 a7 = bf4_to_f4(hs4[(size_t)s7 * 16 + l]);
            acc.x += (fmaf(a0.x, d0, a1.x * d1) + fmaf(a2.x, d2, a3.x * d3))
                   + (fmaf(a4.x, d4, a5.x * d5) + fmaf(a6.x, d6, a7.x * d7));
            acc.y += (fmaf(a0.y, d0, a1.y * d1) + fmaf(a2.y, d2, a3.y * d3))
                   + (fmaf(a4.y, d4, a5.y * d5) + fmaf(a6.y, d6, a7.y * d7));
            acc.z += (fmaf(a0.z, d0, a1.z * d1) + fmaf(a2.z, d2, a3.z * d3))
                   + (fmaf(a4.z, d4, a5.z * d5) + fmaf(a6.z, d6, a7.z * d7));
            acc.w += (fmaf(a0.w, d0, a1.w * d1) + fmaf(a2.w, d2, a3.w * d3))
                   + (fmaf(a4.w, d4, a5.w * d5) + fmaf(a6.w, d6, a7.w * d7));
        }
        for (; j + 1 < end; j += 2) {
            int s0 = csr[j], s1 = csr[j + 1];
            float d0 = dinv[s0], d1 = dinv[s1];
            float4 a0 = bf4_to_f4(hs4[(size_t)s0 * 16 + l]);
            float4 a1 = bf4_to_f4(hs4[(size_t)s1 * 16 + l]);
            acc.x += fmaf(a0.x, d0, a1.x * d1);
            acc.y += fmaf(a0.y, d0, a1.y * d1);
            acc.z += fmaf(a0.z, d0, a1.z * d1);
            acc.w += fmaf(a0.w, d0, a1.w * d1);
        }
        if (j < end) {
            int s0 = csr[j];
            float d0 = dinv[s0];
            float4 a0 = bf4_to_f4(hs4[(size_t)s0 * 16 + l]);
            acc.x = fmaf(a0.x, d0, acc.x); acc.y = fmaf(a0.y, d0, acc.y);
            acc.z = fmaf(a0.z, d0, acc.z); acc.w = fmaf(a0.w, d0, acc.w);
        }
        float4 bb = ((const float4*)b1)[l];
        float4 h;
        h.x = fmaxf(fmaf(di_n, acc.x, bb.x), 0.f);
        h.y = fmaxf(fmaf(di_n, acc.y, bb.y), 0.f);
        h.z = fmaxf(fmaf(di_n, acc.z, bb.z), 0.f);
        h.w = fmaxf(fmaf(di_n, acc.w, bb.w), 0.f);
        *((float4*)&h1s[g][l * 4]) = h;
    }
    __syncthreads();
    int r = tid >> 4, o = tid & 15;     // 16 rows x 16 out-cols
    int n2 = blockIdx.x * 16 + r;
    if (n2 < N) {
        float acc = 0.f;
        #pragma unroll
        for (int jj = 0; jj < FH; ++jj)
            acc = fmaf(h1s[r][jj], W2s[jj * FO + o], acc);
        hs2b[(size_t)n2 * FO + o] = f2bf(acc * dinv[n2]);   // pre-scaled bf16
    }
}

// ---------------------------------------------------------------------------
// Kernel: layer-2 PULL aggregation (8 gathers in flight) + bias + log_softmax.
// hs2b table is 3.2 MB -> fits per-XCD L2; gathers are 2B/lane.
// ---------------------------------------------------------------------------
__launch_bounds__(256)
__global__ void agg2_softmax_kernel(const unsigned short* __restrict__ hs2b,
                                    const int* __restrict__ csr,
                                    const int* __restrict__ offs, const float* __restrict__ dinv,
                                    const float* __restrict__ b2, float* __restrict__ out, int N) {
    int tid = threadIdx.x;
    int g = tid >> 4, o = tid & 15;
    int n = blockIdx.x * 16 + g;
    float v = 0.f;
    if (n < N) {
        float acc = bf2f(hs2b[(size_t)n * 16 + o]);    // self loop (pre-scaled)
        int j = offs[n], end = offs[n + 1];
        for (; j + 7 < end; j += 8) {
            int s0 = csr[j],     s1 = csr[j + 1], s2 = csr[j + 2], s3 = csr[j + 3];
            int s4 = csr[j + 4], s5 = csr[j + 5], s6 = csr[j + 6], s7 = csr[j + 7];
            float t0 = bf2f(hs2b[(size_t)s0 * 16 + o]) + bf2f(hs2b[(size_t)s1 * 16 + o]);
            float t1 = bf2f(hs2b[(size_t)s2 * 16 + o]) + bf2f(hs2b[(size_t)s3 * 16 + o]);
            float t2 = bf2f(hs2b[(size_t)s4 * 16 + o]) + bf2f(hs2b[(size_t)s5 * 16 + o]);
            float t3 = bf2f(hs2b[(size_t)s6 * 16 + o]) + bf2f(hs2b[(size_t)s7 * 16 + o]);
            acc += (t0 + t1) + (t2 + t3);
        }
        for (; j < end; ++j) acc += bf2f(hs2b[(size_t)csr[j] * 16 + o]);
        v = fmaf(dinv[n], acc, b2[o]);
    }
    float m = v;
    #pragma unroll
    for (int s = 8; s >= 1; s >>= 1) m = fmaxf(m, __shfl_xor(m, s, 64));
    float ex = __expf(v - m);
    float sum = ex;
    #pragma unroll
    for (int s = 8; s >= 1; s >>= 1) sum += __shfl_xor(sum, s, 64);
    if (n < N) out[(size_t)n * FO + o] = v - m - __logf(sum);
}

// ---------------------------------------------------------------------------
extern "C" void kernel_launch(void* const* d_in, const int* in_sizes, int n_in,
                              void* d_out, int out_size, void* d_ws, size_t ws_size,
                              hipStream_t stream) {
    const float* x  = (const float*)d_in[0];
    const int*   ei = (const int*)d_in[1];     // int32
    const float* W1 = (const float*)d_in[2];
    const float* b1 = (const float*)d_in[3];
    const float* W2 = (const float*)d_in[4];
    const float* b2 = (const float*)d_in[5];
    float* out = (float*)d_out;

    const int N = in_sizes[0] / FIN;
    const int E = in_sizes[1] / 2;
    const int NCH  = (E + EPB_HIST - 1) / EPB_HIST;  // hist blocks
    const int NCB  = (E + EPB_BIN - 1) / EPB_BIN;    // binning blocks
    const int NB4  = (N + BW - 1) / BW;              // buckets actually used
    const int G1T  = (N + 63) / 64;                  // gemm 64-row tiles
    const int GA   = (N + 15) / 16;                  // agg blocks

    char* ws = (char*)d_ws;
    size_t off = 0;
    auto alloc = [&](size_t bytes) -> void* {
        off = (off + 255) & ~(size_t)255;
        void* p = ws + off;
        off += bytes;
        return p;
    };
    float*          dinv  = (float*)alloc((size_t)N * 4);               //  0.4 MB
    unsigned short* hsb   = (unsigned short*)alloc((size_t)N * FH * 2); // 12.8 MB
    unsigned short* hs2b  = (unsigned short*)alloc((size_t)N * FO * 2); //  3.2 MB
    int*            offs  = (int*)alloc((size_t)(N + 1) * 4);           //  0.4 MB
    int*            bcnt  = (int*)alloc(NBUCK * 4);
    int*            bbase = (int*)alloc((NBUCK + 1) * 4);
    int*            gcur  = (int*)alloc(NBUCK * 4);
    // ebuf + csr (2*E ints = 12.8 MB): in ws if it fits, else alias the x
    // input buffer (25.6 MB, dead after the gemm phase; harness restores d_in
    // before every launch; ws_size constant -> capture-stable branch).
    unsigned* ebuf;
    int*      csr;
    bool ws_fits = (ws_size >= off + 512 + (size_t)E * 8);
    if (ws_fits) {
        ebuf = (unsigned*)alloc((size_t)E * 4);
        csr  = (int*)     alloc((size_t)E * 4);
    } else {
        ebuf = (unsigned*)x;
        csr  = (int*)x + E;
    }

    hipMemsetAsync(bcnt, 0, NBUCK * 4, stream);

    hist_kernel<<<NCH, 256, 0, stream>>>(ei, E, bcnt);
    bucket_scan_kernel<<<1, NBUCK, 0, stream>>>(bcnt, bbase, gcur, offs, N, E);
    if (ws_fits) {
        // Overlap: binning blocks first (latency-bound), gemm blocks backfill.
        gemm1_binning_kernel<<<NCB + G1T, 256, 0, stream>>>(x, W1, hsb, ei, E,
                                                            gcur, ebuf, N, NCB);
    } else {
        // ebuf aliases x: gemm must fully precede binning.
        gemm1_binning_kernel<<<G1T, 256, 0, stream>>>(x, W1, hsb, ei, E,
                                                      gcur, ebuf, N, 0);
        binning_kernel<<<NCB, 256, 0, stream>>>(ei, E, gcur, ebuf);
    }
    bucket_csr_kernel<<<NB4, 256, 0, stream>>>(ebuf, bbase, csr, offs, dinv, N);
    agg1_gemm2_kernel<<<GA, 256, 0, stream>>>(hsb, csr, offs, dinv, b1, W2, hs2b, N);
    agg2_softmax_kernel<<<GA, 256, 0, stream>>>(hs2b, csr, offs, dinv, b2, out, N);
}

// Round 10
// 213.152 us; speedup vs baseline: 1.1254x; 1.1254x over previous
//
#include <hip/hip_runtime.h>

// Feature dims fixed by the problem
constexpr int FIN = 64;   // input features
constexpr int FH  = 64;   // hidden
constexpr int FO  = 16;   // output

// edge_index arrives as int32 (harness integer convention), flat [2][E]:
// src = ei[e], dst = ei[e + E].

// Bucket sort parameters: bucket = dst >> 7 (128 nodes per bucket).
constexpr int BSH      = 7;
constexpr int BW       = 1 << BSH;  // 128 nodes / bucket
constexpr int NBUCK    = 1024;      // covers N up to 131072
constexpr int EPB_HIST = 16384;     // edges per hist block
constexpr int EPB_BIN  = 4096;      // edges per binning block

// bf16 helpers (manual RNE; exact expand)
__device__ inline unsigned short f2bf(float f) {
    unsigned u = __float_as_uint(f);
    return (unsigned short)((u + 0x7FFFu + ((u >> 16) & 1u)) >> 16);
}
__device__ inline float bf2f(unsigned short h) {
    return __uint_as_float((unsigned)h << 16);
}
__device__ inline float4 bf4_to_f4(ushort4 u) {
    float4 f;
    f.x = bf2f(u.x); f.y = bf2f(u.y); f.z = bf2f(u.z); f.w = bf2f(u.w);
    return f;
}

// ---------------------------------------------------------------------------
// Kernel: dst-bucket histogram (standalone; 98 blocks, cheap).
// ---------------------------------------------------------------------------
__launch_bounds__(256)
__global__ void hist_kernel(const int* __restrict__ ei, int E, int* __restrict__ bcnt) {
    __shared__ int lh[NBUCK];
    int t = threadIdx.x;
    for (int i = t; i < NBUCK; i += 256) lh[i] = 0;
    __syncthreads();
    int base = blockIdx.x * EPB_HIST;
    int lim  = min(E, base + EPB_HIST);
    for (int e = base + t; e < lim; e += 256)
        atomicAdd(&lh[ei[E + e] >> BSH], 1);
    __syncthreads();
    for (int b = t; b < NBUCK; b += 256) {
        int c = lh[b];
        if (c > 0) atomicAdd(&bcnt[b], c);
    }
}

// ---------------------------------------------------------------------------
// Kernel: exclusive scan of bucket counts -> bbase[NBUCK+1], init gcur.
// Single block of 1024 threads. Also writes offs[N] = E.
// ---------------------------------------------------------------------------
__launch_bounds__(1024)
__global__ void bucket_scan_kernel(const int* __restrict__ bcnt, int* __restrict__ bbase,
                                   int* __restrict__ gcur, int* __restrict__ offs,
                                   int N, int E) {
    __shared__ int s[NBUCK];
    int t = threadIdx.x;
    int v = bcnt[t];
    s[t] = v;
    __syncthreads();
    for (int d = 1; d < NBUCK; d <<= 1) {
        int u = (t >= d) ? s[t - d] : 0;
        __syncthreads();
        s[t] += u;
        __syncthreads();
    }
    int ex = s[t] - v;
    bbase[t] = ex;
    gcur[t]  = ex;
    if (t == NBUCK - 1) {
        bbase[NBUCK] = s[t];   // == E
        offs[N] = E;
    }
}

// ---------------------------------------------------------------------------
// Binning device body: reserve contiguous per-bucket runs, write each edge
// once as packed word src | (dst & 127) << 17 (N < 2^17).
// ---------------------------------------------------------------------------
__device__ inline void binning_body(const int* __restrict__ ei, int E, int chunk,
                                    int* __restrict__ gcur, unsigned* __restrict__ ebuf,
                                    int* lh) {
    int t = threadIdx.x;
    for (int i = t; i < NBUCK; i += 256) lh[i] = 0;
    __syncthreads();
    int base = chunk * EPB_BIN;
    int lim  = min(E, base + EPB_BIN);
    for (int e = base + t; e < lim; e += 256)
        atomicAdd(&lh[ei[E + e] >> BSH], 1);
    __syncthreads();
    for (int b = t; b < NBUCK; b += 256) {
        int c = lh[b];
        lh[b] = (c > 0) ? atomicAdd(&gcur[b], c) : 0;   // run base -> running cursor
    }
    __syncthreads();
    for (int e = base + t; e < lim; e += 256) {
        int d = ei[E + e];
        int srcv = ei[e];
        int pos = atomicAdd(&lh[d >> BSH], 1);
        ebuf[pos] = (unsigned)srcv | ((unsigned)(d & (BW - 1)) << 17);
    }
}

__launch_bounds__(256)
__global__ void binning_kernel(const int* __restrict__ ei, int E,
                               int* __restrict__ gcur, unsigned* __restrict__ ebuf) {
    __shared__ int lh[NBUCK];
    binning_body(ei, E, blockIdx.x, gcur, ebuf, lh);
}

// ---------------------------------------------------------------------------
// Fused kernel: blocks [0, NBIN) do binning (latency-bound, start first);
// blocks [NBIN, NBIN+G1T) do hs_bf16 = bf16(x @ W1): 64-row tile, 4x4 per
// thread. W1 in LDS (16 KB, conflict-free); x read directly from global
// (16-lane broadcast per row, L1/L2-resident). No manual prefetch, partial
// unroll, __launch_bounds__(256,4) caps VGPRs <= 128 (round-9 hit 240 VGPRs
// from full unroll -> 9.6% occupancy; this is the fix).
// ---------------------------------------------------------------------------
__launch_bounds__(256, 4)
__global__ void gemm1_binning_kernel(const float* __restrict__ x, const float* __restrict__ W1,
                                     unsigned short* __restrict__ hsb,
                                     const int* __restrict__ ei, int E,
                                     int* __restrict__ gcur, unsigned* __restrict__ ebuf,
                                     int N, int NBIN) {
    __shared__ float smem[FIN * FH];    // 16 KB: Ws for gemm, lh (4 KB) for binning
    int tid = threadIdx.x;
    if ((int)blockIdx.x < NBIN) {
        binning_body(ei, E, (int)blockIdx.x, gcur, ebuf, (int*)smem);
        return;
    }
    // ---- GEMM phase ----
    float* Ws = smem;                  // [64][64] row-major (k, col)
    {
        const float4* W14 = (const float4*)W1;
        float4* Ws4 = (float4*)smem;
        for (int i = tid; i < 1024; i += 256) Ws4[i] = W14[i];
    }
    __syncthreads();
    int cg = tid & 15;                 // col group: cols cg*4..+3
    int rg = tid >> 4;                 // row group: rows rg*4..+3
    int rowBase = ((int)blockIdx.x - NBIN) * 64;
    int r0 = rowBase + rg * 4;
    const float4* x4 = (const float4*)x;
    // clamped row indices (loads never fault; OOB rows' stores are predicated)
    size_t ra = (size_t)min(r0 + 0, N - 1) * 16;
    size_t rb = (size_t)min(r0 + 1, N - 1) * 16;
    size_t rc = (size_t)min(r0 + 2, N - 1) * 16;
    size_t rd = (size_t)min(r0 + 3, N - 1) * 16;
    float4 acc0 = {0,0,0,0}, acc1 = {0,0,0,0}, acc2 = {0,0,0,0}, acc3 = {0,0,0,0};
    #pragma unroll 2
    for (int kc = 0; kc < 16; ++kc) {
        float4 xa0 = x4[ra + kc];
        float4 xa1 = x4[rb + kc];
        float4 xa2 = x4[rc + kc];
        float4 xa3 = x4[rd + kc];
        const float* xa0f = (const float*)&xa0;
        const float* xa1f = (const float*)&xa1;
        const float* xa2f = (const float*)&xa2;
        const float* xa3f = (const float*)&xa3;
        #pragma unroll
        for (int j = 0; j < 4; ++j) {
            float4 wv = *(const float4*)&Ws[(kc * 4 + j) * FH + cg * 4];
            float v0 = xa0f[j], v1 = xa1f[j], v2 = xa2f[j], v3 = xa3f[j];
            acc0.x = fmaf(v0, wv.x, acc0.x); acc0.y = fmaf(v0, wv.y, acc0.y);
            acc0.z = fmaf(v0, wv.z, acc0.z); acc0.w = fmaf(v0, wv.w, acc0.w);
            acc1.x = fmaf(v1, wv.x, acc1.x); acc1.y = fmaf(v1, wv.y, acc1.y);
            acc1.z = fmaf(v1, wv.z, acc1.z); acc1.w = fmaf(v1, wv.w, acc1.w);
            acc2.x = fmaf(v2, wv.x, acc2.x); acc2.y = fmaf(v2, wv.y, acc2.y);
            acc2.z = fmaf(v2, wv.z, acc2.z); acc2.w = fmaf(v2, wv.w, acc2.w);
            acc3.x = fmaf(v3, wv.x, acc3.x); acc3.y = fmaf(v3, wv.y, acc3.y);
            acc3.z = fmaf(v3, wv.z, acc3.z); acc3.w = fmaf(v3, wv.w, acc3.w);
        }
    }
    ushort4* hsb4 = (ushort4*)hsb;
    if (r0 + 0 < N) hsb4[(size_t)(r0 + 0) * 16 + cg] =
        make_ushort4(f2bf(acc0.x), f2bf(acc0.y), f2bf(acc0.z), f2bf(acc0.w));
    if (r0 + 1 < N) hsb4[(size_t)(r0 + 1) * 16 + cg] =
        make_ushort4(f2bf(acc1.x), f2bf(acc1.y), f2bf(acc1.z), f2bf(acc1.w));
    if (r0 + 2 < N) hsb4[(size_t)(r0 + 2) * 16 + cg] =
        make_ushort4(f2bf(acc2.x), f2bf(acc2.y), f2bf(acc2.z), f2bf(acc2.w));
    if (r0 + 3 < N) hsb4[(size_t)(r0 + 3) * 16 + cg] =
        make_ushort4(f2bf(acc3.x), f2bf(acc3.y), f2bf(acc3.z), f2bf(acc3.w));
}

// ---------------------------------------------------------------------------
// Kernel: per-bucket CSR build + dinv + offs. One block per bucket; all csr
// stores land in the block's own contiguous region (single-owner lines).
// ---------------------------------------------------------------------------
__launch_bounds__(256)
__global__ void bucket_csr_kernel(const unsigned* __restrict__ ebuf,
                                  const int* __restrict__ bbase,
                                  int* __restrict__ csr, int* __restrict__ offs,
                                  float* __restrict__ dinv, int N) {
    __shared__ int cnt[BW], sc[BW], cur[BW];
    int t = threadIdx.x;
    int b = blockIdx.x;
    if (t < BW) cnt[t] = 0;
    __syncthreads();
    int beg = bbase[b], end = bbase[b + 1];
    for (int i = beg + t; i < end; i += 256)
        atomicAdd(&cnt[ebuf[i] >> 17], 1);
    __syncthreads();
    if (t < BW) sc[t] = cnt[t];
    __syncthreads();
    for (int d = 1; d < BW; d <<= 1) {
        int u = (t < BW && t >= d) ? sc[t - d] : 0;
        __syncthreads();
        if (t < BW) sc[t] += u;
        __syncthreads();
    }
    int nodeBase = b << BSH;
    if (t < BW) {
        int node = nodeBase + t;
        int ex = beg + sc[t] - cnt[t];
        cur[t] = ex;
        if (node < N) {
            offs[node] = ex;
            dinv[node] = rsqrtf((float)(cnt[t] + 1));
        }
    }
    __syncthreads();
    for (int i = beg + t; i < end; i += 256) {
        unsigned w = ebuf[i];
        int pos = atomicAdd(&cur[w >> 17], 1);
        csr[pos] = (int)(w & 0x1FFFF);
    }
}

// ---------------------------------------------------------------------------
// Kernel: layer-1 PULL aggregation (bf16 gathers, 8 in flight, per-src dinv
// scale in-reg) fused with finalize1 + GEMM2; writes hs2 pre-scaled as bf16.
// 16 nodes/block; 16 lanes per node, lane owns one ushort4 chunk (4 feats).
// ---------------------------------------------------------------------------
__launch_bounds__(256)
__global__ void agg1_gemm2_kernel(const unsigned short* __restrict__ hsb,
                                  const int* __restrict__ csr,
                                  const int* __restrict__ offs, const float* __restrict__ dinv,
                                  const float* __restrict__ b1, const float* __restrict__ W2,
                                  unsigned short* __restrict__ hs2b, int N) {
    __shared__ float W2s[FH * FO];       // 4 KB
    __shared__ float h1s[16][68];        // 68-float row stride (16B-aligned, non-pow2)
    const ushort4* hs4 = (const ushort4*)hsb;   // 16 ushort4 per row
    int tid = threadIdx.x;
    for (int i = tid; i < FH * FO; i += 256) W2s[i] = W2[i];
    int g = tid >> 4, l = tid & 15;
    int n = blockIdx.x * 16 + g;
    if (n < N) {
        float di_n = dinv[n];
        float4 self = bf4_to_f4(hs4[(size_t)n * 16 + l]);
        float4 acc;
        acc.x = self.x * di_n; acc.y = self.y * di_n;
        acc.z = self.z * di_n; acc.w = self.w * di_n;
        int j = offs[n], end = offs[n + 1];
        for (; j + 7 < end; j += 8) {              // 8 gathers in flight
            int s0 = csr[j],     s1 = csr[j + 1], s2 = csr[j + 2], s3 = csr[j + 3];
            int s4 = csr[j + 4], s5 = csr[j + 5], s6 = csr[j + 6], s7 = csr[j + 7];
            float d0 = dinv[s0], d1 = dinv[s1], d2 = dinv[s2], d3 = dinv[s3];
            float d4 = dinv[s4], d5 = dinv[s5], d6 = dinv[s6], d7 = dinv[s7];
            float4 a0 = bf4_to_f4(hs4[(size_t)s0 * 16 + l]);
            float4 a1 = bf4_to_f4(hs4[(size_t)s1 * 16 + l]);
            float4 a2 = bf4_to_f4(hs4[(size_t)s2 * 16 + l]);
            float4 a3 = bf4_to_f4(hs4[(size_t)s3 * 16 + l]);
            float4 a4 = bf4_to_f4(hs4[(size_t)s4 * 16 + l]);
            float4 a5 = bf4_to_f4(hs4[(size_t)s5 * 16 + l]);
            float4 a6 = bf4_to_f4(hs4[(size_t)s6 * 16 + l]);
            float4 a7 = bf4_to_f4(hs4[(size_t)s7 * 16 + l]);
            acc.x += (fmaf(a0.x, d0, a1.x * d1) + fmaf(a2.x, d2, a3.x * d3))
                   + (fmaf(a4.x, d4, a5.x * d5) + fmaf(a6.x, d6, a7.x * d7));
            acc.y += (fmaf(a0.y, d0, a1.y * d1) + fmaf(a2.y, d2, a3.y * d3))
                   + (fmaf(a4.y, d4, a5.y * d5) + fmaf(a6.y, d6, a7.y * d7));
            acc.z += (fmaf(a0.z, d0, a1.z * d1) + fmaf(a2.z, d2, a3.z * d3))
                   + (fmaf(a4.z, d4, a5.z * d5) + fmaf(a6.z, d6, a7.z * d7));
            acc.w += (fmaf(a0.w, d0, a1.w * d1) + fmaf(a2.w, d2, a3.w * d3))
                   + (fmaf(a4.w, d4, a5.w * d5) + fmaf(a6.w, d6, a7.w * d7));
        }
        for (; j + 1 < end; j += 2) {
            int s0 = csr[j], s1 = csr[j + 1];
            float d0 = dinv[s0], d1 = dinv[s1];
            float4 a0 = bf4_to_f4(hs4[(size_t)s0 * 16 + l]);
            float4 a1 = bf4_to_f4(hs4[(size_t)s1 * 16 + l]);
            acc.x += fmaf(a0.x, d0, a1.x * d1);
            acc.y += fmaf(a0.y, d0, a1.y * d1);
            acc.z += fmaf(a0.z, d0, a1.z * d1);
            acc.w += fmaf(a0.w, d0, a1.w * d1);
        }
        if (j < end) {
            int s0 = csr[j];
            float d0 = dinv[s0];
            float4 a0 = bf4_to_f4(hs4[(size_t)s0 * 16 + l]);
            acc.x = fmaf(a0.x, d0, acc.x); acc.y = fmaf(a0.y, d0, acc.y);
            acc.z = fmaf(a0.z, d0, acc.z); acc.w = fmaf(a0.w, d0, acc.w);
        }
        float4 bb = ((const float4*)b1)[l];
        float4 h;
        h.x = fmaxf(fmaf(di_n, acc.x, bb.x), 0.f);
        h.y = fmaxf(fmaf(di_n, acc.y, bb.y), 0.f);
        h.z = fmaxf(fmaf(di_n, acc.z, bb.z), 0.f);
        h.w = fmaxf(fmaf(di_n, acc.w, bb.w), 0.f);
        *((float4*)&h1s[g][l * 4]) = h;
    }
    __syncthreads();
    int r = tid >> 4, o = tid & 15;     // 16 rows x 16 out-cols
    int n2 = blockIdx.x * 16 + r;
    if (n2 < N) {
        float acc = 0.f;
        #pragma unroll
        for (int jj = 0; jj < FH; ++jj)
            acc = fmaf(h1s[r][jj], W2s[jj * FO + o], acc);
        hs2b[(size_t)n2 * FO + o] = f2bf(acc * dinv[n2]);   // pre-scaled bf16
    }
}

// ---------------------------------------------------------------------------
// Kernel: layer-2 PULL aggregation (8 gathers in flight) + bias + log_softmax.
// hs2b table is 3.2 MB -> fits per-XCD L2; gathers are 2B/lane.
// ---------------------------------------------------------------------------
__launch_bounds__(256)
__global__ void agg2_softmax_kernel(const unsigned short* __restrict__ hs2b,
                                    const int* __restrict__ csr,
                                    const int* __restrict__ offs, const float* __restrict__ dinv,
                                    const float* __restrict__ b2, float* __restrict__ out, int N) {
    int tid = threadIdx.x;
    int g = tid >> 4, o = tid & 15;
    int n = blockIdx.x * 16 + g;
    float v = 0.f;
    if (n < N) {
        float acc = bf2f(hs2b[(size_t)n * 16 + o]);    // self loop (pre-scaled)
        int j = offs[n], end = offs[n + 1];
        for (; j + 7 < end; j += 8) {
            int s0 = csr[j],     s1 = csr[j + 1], s2 = csr[j + 2], s3 = csr[j + 3];
            int s4 = csr[j + 4], s5 = csr[j + 5], s6 = csr[j + 6], s7 = csr[j + 7];
            float t0 = bf2f(hs2b[(size_t)s0 * 16 + o]) + bf2f(hs2b[(size_t)s1 * 16 + o]);
            float t1 = bf2f(hs2b[(size_t)s2 * 16 + o]) + bf2f(hs2b[(size_t)s3 * 16 + o]);
            float t2 = bf2f(hs2b[(size_t)s4 * 16 + o]) + bf2f(hs2b[(size_t)s5 * 16 + o]);
            float t3 = bf2f(hs2b[(size_t)s6 * 16 + o]) + bf2f(hs2b[(size_t)s7 * 16 + o]);
            acc += (t0 + t1) + (t2 + t3);
        }
        for (; j < end; ++j) acc += bf2f(hs2b[(size_t)csr[j] * 16 + o]);
        v = fmaf(dinv[n], acc, b2[o]);
    }
    float m = v;
    #pragma unroll
    for (int s = 8; s >= 1; s >>= 1) m = fmaxf(m, __shfl_xor(m, s, 64));
    float ex = __expf(v - m);
    float sum = ex;
    #pragma unroll
    for (int s = 8; s >= 1; s >>= 1) sum += __shfl_xor(sum, s, 64);
    if (n < N) out[(size_t)n * FO + o] = v - m - __logf(sum);
}

// ---------------------------------------------------------------------------
extern "C" void kernel_launch(void* const* d_in, const int* in_sizes, int n_in,
                              void* d_out, int out_size, void* d_ws, size_t ws_size,
                              hipStream_t stream) {
    const float* x  = (const float*)d_in[0];
    const int*   ei = (const int*)d_in[1];     // int32
    const float* W1 = (const float*)d_in[2];
    const float* b1 = (const float*)d_in[3];
    const float* W2 = (const float*)d_in[4];
    const float* b2 = (const float*)d_in[5];
    float* out = (float*)d_out;

    const int N = in_sizes[0] / FIN;
    const int E = in_sizes[1] / 2;
    const int NCH  = (E + EPB_HIST - 1) / EPB_HIST;  // hist blocks
    const int NCB  = (E + EPB_BIN - 1) / EPB_BIN;    // binning blocks
    const int NB4  = (N + BW - 1) / BW;              // buckets actually used
    const int G1T  = (N + 63) / 64;                  // gemm 64-row tiles
    const int GA   = (N + 15) / 16;                  // agg blocks

    char* ws = (char*)d_ws;
    size_t off = 0;
    auto alloc = [&](size_t bytes) -> void* {
        off = (off + 255) & ~(size_t)255;
        void* p = ws + off;
        off += bytes;
        return p;
    };
    float*          dinv  = (float*)alloc((size_t)N * 4);               //  0.4 MB
    unsigned short* hsb   = (unsigned short*)alloc((size_t)N * FH * 2); // 12.8 MB
    unsigned short* hs2b  = (unsigned short*)alloc((size_t)N * FO * 2); //  3.2 MB
    int*            offs  = (int*)alloc((size_t)(N + 1) * 4);           //  0.4 MB
    int*            bcnt  = (int*)alloc(NBUCK * 4);
    int*            bbase = (int*)alloc((NBUCK + 1) * 4);
    int*            gcur  = (int*)alloc(NBUCK * 4);
    // ebuf + csr (2*E ints = 12.8 MB): in ws if it fits, else alias the x
    // input buffer (25.6 MB, dead after the gemm phase; harness restores d_in
    // before every launch; ws_size constant -> capture-stable branch).
    unsigned* ebuf;
    int*      csr;
    bool ws_fits = (ws_size >= off + 512 + (size_t)E * 8);
    if (ws_fits) {
        ebuf = (unsigned*)alloc((size_t)E * 4);
        csr  = (int*)     alloc((size_t)E * 4);
    } else {
        ebuf = (unsigned*)x;
        csr  = (int*)x + E;
    }

    hipMemsetAsync(bcnt, 0, NBUCK * 4, stream);

    hist_kernel<<<NCH, 256, 0, stream>>>(ei, E, bcnt);
    bucket_scan_kernel<<<1, NBUCK, 0, stream>>>(bcnt, bbase, gcur, offs, N, E);
    if (ws_fits) {
        // Overlap: binning blocks first (latency-bound), gemm blocks backfill.
        gemm1_binning_kernel<<<NCB + G1T, 256, 0, stream>>>(x, W1, hsb, ei, E,
                                                            gcur, ebuf, N, NCB);
    } else {
        // ebuf aliases x: gemm must fully precede binning.
        gemm1_binning_kernel<<<G1T, 256, 0, stream>>>(x, W1, hsb, ei, E,
                                                      gcur, ebuf, N, 0);
        binning_kernel<<<NCB, 256, 0, stream>>>(ei, E, gcur, ebuf);
    }
    bucket_csr_kernel<<<NB4, 256, 0, stream>>>(ebuf, bbase, csr, offs, dinv, N);
    agg1_gemm2_kernel<<<GA, 256, 0, stream>>>(hsb, csr, offs, dinv, b1, W2, hs2b, N);
    agg2_softmax_kernel<<<GA, 256, 0, stream>>>(hs2b, csr, offs, dinv, b2, out, N);
}